// Round 17
// baseline (70.683 us; speedup 1.0000x reference)
//
#include <hip/hip_runtime.h>
#include <hip/hip_bf16.h>
#include <math.h>

// dims fixed by setup_inputs: N=8, H=8, D=64, L=M=1024, C=64

typedef __attribute__((ext_vector_type(4)))  float    f32x4;
typedef __attribute__((ext_vector_type(16))) float    f32x16;
typedef __attribute__((ext_vector_type(8)))  __bf16   bf16x8;
typedef __attribute__((ext_vector_type(8)))  short    s16x8;
typedef __attribute__((ext_vector_type(4)))  short    s16x4;
typedef __attribute__((ext_vector_type(2)))  unsigned u32x2;
typedef __attribute__((ext_vector_type(4)))  unsigned u32x4;

// ws layout:
//   Kt  bf16 [64][1024][64]   @ 0        (8 MiB)
//   Vb  bf16 [64][64][1024]   @ 8 MiB    (8 MiB)
//   ss  fp32[64]              @ 16 MiB
//   GM  fp32 [512][6][1024]   @ 32 MiB   (12 MiB)  (2-stage k1 only)
#define KT_OFF 0u
#define VB_OFF (8u*1024u*1024u)
#define SS_OFF (16u*1024u*1024u)
#define GM_OFF (32u*1024u*1024u)
#define BASE_WS_NEED (16u*1024u*1024u + 4096u)
#define GRAM2_WS_NEED (48u*1024u*1024u)

static __device__ __forceinline__ short bf16s(float f) {
  return __builtin_bit_cast(short, (__bf16)f);
}
static __device__ __forceinline__ unsigned pkbf(float lo, float hi) {
  unsigned l = (unsigned)__builtin_bit_cast(unsigned short, (__bf16)lo);
  unsigned h = (unsigned)__builtin_bit_cast(unsigned short, (__bf16)hi);
  return l | (h << 16);
}
static __device__ __forceinline__ bf16x8 cvt8(const float* p) {
  f32x4 a = *(const f32x4*)p;
  f32x4 b = *(const f32x4*)(p + 4);
  bf16x8 r;
  r[0]=(__bf16)a[0]; r[1]=(__bf16)a[1]; r[2]=(__bf16)a[2]; r[3]=(__bf16)a[3];
  r[4]=(__bf16)b[0]; r[5]=(__bf16)b[1]; r[6]=(__bf16)b[2]; r[7]=(__bf16)b[3];
  return r;
}
static __device__ __forceinline__ f32x16 z16() {
  f32x16 z;
  #pragma unroll
  for (int i = 0; i < 16; ++i) z[i] = 0.f;
  return z;
}
static __device__ __forceinline__ bf16x8 mk8(unsigned a, unsigned b, unsigned c, unsigned d) {
  u32x4 u; u[0]=a; u[1]=b; u[2]=c; u[3]=d;
  return __builtin_bit_cast(bf16x8, u);
}
static __device__ __forceinline__ void gll16(const void* g, void* l) {
  __builtin_amdgcn_global_load_lds(
      (const __attribute__((address_space(1))) void*)g,
      (__attribute__((address_space(3))) void*)l, 16, 0, 0);
}

// ---- K0: blocks<1024: K [bh][d][m] -> Kt [bh][m][d] bf16; rest: V -> Vb bf16 --
__global__ __launch_bounds__(256) void k0_prep(const float* __restrict__ K,
                                               const float* __restrict__ V,
                                               short* __restrict__ Kt,
                                               short* __restrict__ Vb) {
  int tid = threadIdx.x;
  if (blockIdx.x < 1024) {
    int bh = blockIdx.x >> 4;
    int m0 = (blockIdx.x & 15) << 6;
    __shared__ short tile[64][72];          // [m][d], +8 pad
    int d = tid >> 2;
    #pragma unroll
    for (int it = 0; it < 4; ++it) {
      int mc4 = (tid & 3) + (it << 2);
      const f32x4 v = *(const f32x4*)(K + (((size_t)(bh*64 + d)) << 10) + m0 + (mc4 << 2));
      #pragma unroll
      for (int j = 0; j < 4; ++j) tile[mc4*4 + j][d] = bf16s(v[j]);
    }
    __syncthreads();
    int m = tid >> 2, q = tid & 3;
    s16x8 o0, o1;
    #pragma unroll
    for (int j = 0; j < 8; ++j) { o0[j] = tile[m][q*16 + j]; o1[j] = tile[m][q*16 + 8 + j]; }
    short* dst = Kt + ((size_t)bh << 16) + ((size_t)(m0 + m) << 6) + (q << 4);
    *(s16x8*)dst = o0;
    *(s16x8*)(dst + 8) = o1;
  } else {
    // streaming fp32 -> bf16 convert of V (no transpose; PV consumes [c][m] rows)
    size_t base = ((size_t)(blockIdx.x - 1024)) << 13;   // 8192 elems per block
    #pragma unroll
    for (int it = 0; it < 8; ++it) {
      size_t idx = base + ((size_t)it << 10) + (tid << 2);
      f32x4 x = *(const f32x4*)(V + idx);
      s16x4 y;
      #pragma unroll
      for (int j = 0; j < 4; ++j) y[j] = bf16s(x[j]);
      *(s16x4*)(Vb + idx) = y;
    }
  }
}

// ---- K1a (stage A): partial Grams per (bh, l-slice) -> gm, full-chip grid ----
__global__ __launch_bounds__(256) void k1a_gram(const float* __restrict__ Q,
                                                const float* __restrict__ K,
                                                float* __restrict__ gm) {
  int bh = blockIdx.x >> 3, sl = blockIdx.x & 7;
  int tid = threadIdx.x, w = tid >> 6, lane = tid & 63;
  int l31 = lane & 31, hi = lane >> 5;
  const float* qlo = Q + ((size_t)bh << 16) + ((size_t)l31 << 10);
  const float* qhi = qlo + (32u << 10);
  const float* klo = K + ((size_t)bh << 16) + ((size_t)l31 << 10);
  const float* khi = klo + (32u << 10);
  f32x16 gq00 = z16(), gq01 = z16(), gq11 = z16();
  f32x16 gk00 = z16(), gk01 = z16(), gk11 = z16();
  #pragma unroll
  for (int lc = 0; lc < 2; ++lc) {
    int loff = (sl << 7) + (w << 5) + (lc << 4) + (hi << 3);
    bf16x8 aql = cvt8(qlo + loff), aqh = cvt8(qhi + loff);
    bf16x8 akl = cvt8(klo + loff), akh = cvt8(khi + loff);
    gq00 = __builtin_amdgcn_mfma_f32_32x32x16_bf16(aql, aql, gq00, 0, 0, 0);
    gq01 = __builtin_amdgcn_mfma_f32_32x32x16_bf16(aql, aqh, gq01, 0, 0, 0);
    gq11 = __builtin_amdgcn_mfma_f32_32x32x16_bf16(aqh, aqh, gq11, 0, 0, 0);
    gk00 = __builtin_amdgcn_mfma_f32_32x32x16_bf16(akl, akl, gk00, 0, 0, 0);
    gk01 = __builtin_amdgcn_mfma_f32_32x32x16_bf16(akl, akh, gk01, 0, 0, 0);
    gk11 = __builtin_amdgcn_mfma_f32_32x32x16_bf16(akh, akh, gk11, 0, 0, 0);
  }
  __shared__ float RQ[4][64][16];
  __shared__ float RK[4][64][16];
  float* gout = gm + ((size_t)blockIdx.x * 6144u);
  #define K1A_RED(GQ_, GK_, TI_)                                            \
    __syncthreads();                                                        \
    _Pragma("unroll")                                                       \
    for (int r = 0; r < 16; ++r) { RQ[w][lane][r] = GQ_[r]; RK[w][lane][r] = GK_[r]; } \
    __syncthreads();                                                        \
    {                                                                       \
      int e = tid & 63, rq = (tid >> 6) << 2;                               \
      f32x4 aq, ak;                                                         \
      _Pragma("unroll")                                                     \
      for (int j = 0; j < 4; ++j) {                                         \
        int r = rq + j;                                                     \
        aq[j] = RQ[0][e][r] + RQ[1][e][r] + RQ[2][e][r] + RQ[3][e][r];      \
        ak[j] = RK[0][e][r] + RK[1][e][r] + RK[2][e][r] + RK[3][e][r];      \
      }                                                                     \
      *(f32x4*)(gout + (TI_)*1024 + (e << 4) + rq) = aq;                    \
      *(f32x4*)(gout + ((TI_) + 3)*1024 + (e << 4) + rq) = ak;              \
    }
  K1A_RED(gq00, gk00, 0)
  K1A_RED(gq01, gk01, 1)
  K1A_RED(gq11, gk11, 2)
  #undef K1A_RED
}

// ---- K1b (stage B): ss[bh] = sum slices, then dot (weights 1,2,1) ------------
__global__ __launch_bounds__(256) void k1b_dot(const float* __restrict__ gm,
                                               float* __restrict__ ss) {
  int bh = blockIdx.x;
  int tid = threadIdx.x, w = tid >> 6, lane = tid & 63;
  float part = 0.f;
  #pragma unroll
  for (int t = 0; t < 3; ++t) {
    f32x4 aq = {0.f, 0.f, 0.f, 0.f}, ak = {0.f, 0.f, 0.f, 0.f};
    #pragma unroll
    for (int s = 0; s < 8; ++s) {
      const float* base = gm + ((size_t)((bh << 3) + s) * 6144u) + (size_t)t*1024u + (tid << 2);
      aq += *(const f32x4*)base;
      ak += *(const f32x4*)(base + 3*1024);
    }
    float d = aq[0]*ak[0] + aq[1]*ak[1] + aq[2]*ak[2] + aq[3]*ak[3];
    part += (t == 1) ? 2.0f * d : d;
  }
  #pragma unroll
  for (int off = 32; off > 0; off >>= 1) part += __shfl_down(part, off, 64);
  __shared__ float red[4];
  if (lane == 0) red[w] = part;
  __syncthreads();
  if (tid == 0) ss[bh] = red[0] + red[1] + red[2] + red[3];
}

// ---- K1 fallback (ws too small): r11-proven 64-block full-Gram version -------
__global__ __launch_bounds__(512) void k1_gram(const float* __restrict__ Q,
                                               const float* __restrict__ K,
                                               float* __restrict__ ss) {
  int bh = blockIdx.x;
  int tid = threadIdx.x, w = tid >> 6, lane = tid & 63;
  int l31 = lane & 31, hi = lane >> 5;
  const float* qlo = Q + ((size_t)bh << 16) + ((size_t)l31 << 10);
  const float* qhi = qlo + (32u << 10);
  const float* klo = K + ((size_t)bh << 16) + ((size_t)l31 << 10);
  const float* khi = klo + (32u << 10);
  f32x16 gq00 = z16(), gq01 = z16(), gq11 = z16();
  f32x16 gk00 = z16(), gk01 = z16(), gk11 = z16();
  for (int lc = 0; lc < 8; ++lc) {
    int loff = (w << 7) + (lc << 4) + (hi << 3);
    bf16x8 aql = cvt8(qlo + loff), aqh = cvt8(qhi + loff);
    bf16x8 akl = cvt8(klo + loff), akh = cvt8(khi + loff);
    gq00 = __builtin_amdgcn_mfma_f32_32x32x16_bf16(aql, aql, gq00, 0, 0, 0);
    gq01 = __builtin_amdgcn_mfma_f32_32x32x16_bf16(aql, aqh, gq01, 0, 0, 0);
    gq11 = __builtin_amdgcn_mfma_f32_32x32x16_bf16(aqh, aqh, gq11, 0, 0, 0);
    gk00 = __builtin_amdgcn_mfma_f32_32x32x16_bf16(akl, akl, gk00, 0, 0, 0);
    gk01 = __builtin_amdgcn_mfma_f32_32x32x16_bf16(akl, akh, gk01, 0, 0, 0);
    gk11 = __builtin_amdgcn_mfma_f32_32x32x16_bf16(akh, akh, gk11, 0, 0, 0);
  }
  __shared__ float RQ[8][64][16];
  __shared__ float RK[8][64][16];
  float part = 0.f;
  #define K1_REDUCE(GQ_, GK_, WT_)                                          \
    __syncthreads();                                                        \
    _Pragma("unroll")                                                       \
    for (int r = 0; r < 16; ++r) { RQ[w][lane][r] = GQ_[r]; RK[w][lane][r] = GK_[r]; } \
    __syncthreads();                                                        \
    if (tid < 256) {                                                        \
      int e = tid & 63, rq = (tid >> 6) << 2;                               \
      _Pragma("unroll")                                                     \
      for (int j = 0; j < 4; ++j) {                                         \
        int r = rq + j;                                                     \
        float aq = 0.f, ak = 0.f;                                           \
        _Pragma("unroll")                                                   \
        for (int ww = 0; ww < 8; ++ww) { aq += RQ[ww][e][r]; ak += RK[ww][e][r]; } \
        part += (WT_) * aq * ak;                                            \
      }                                                                     \
    }
  K1_REDUCE(gq00, gk00, 1.0f)
  K1_REDUCE(gq01, gk01, 2.0f)
  K1_REDUCE(gq11, gk11, 1.0f)
  #undef K1_REDUCE
  #pragma unroll
  for (int off = 32; off > 0; off >>= 1) part += __shfl_down(part, off, 64);
  __shared__ float red[8];
  __syncthreads();
  if (lane == 0) red[w] = part;
  __syncthreads();
  if (tid == 0) {
    float s = 0.f;
    #pragma unroll
    for (int ww = 0; ww < 8; ++ww) s += red[ww];
    ss[bh] = s;
  }
}

// ------- K2: 8 waves share each K/V tile; FULL 16-tile loop, direct norm ------
// 256 blocks (bh x 4 slab of 256 l) x 512 threads. No m-split: no p1/rsp
// traffic, k34 is a plain BN+GELU. Per-wave math identical to r16-proven.
__global__ __launch_bounds__(512) void k2_attn8(const float* __restrict__ Q,
                                                const short* __restrict__ Kt,
                                                const short* __restrict__ Vbf,
                                                const float* __restrict__ ss,
                                                const float* __restrict__ gsim,
                                                float* __restrict__ rv) {
  __shared__ short ldsK[2][4096];   // [64 m][8 chunks of 8 d] bf16, XOR-swizzled
  __shared__ short ldsV[2][4096];   // [64 c][8 chunks of 8 m] bf16, same swizzle
  int b = blockIdx.x;               // 256 blocks: bh x 4 slab
  int bh   = (b & 7) + (((b >> 3) & 7) << 3);   // same bh -> same XCD (round-robin %8)
  int slab = b >> 6;                            // [0,4)
  int l0 = slab << 8;                           // 256 l per block
  int tid = threadIdx.x, w = tid >> 6, lane = tid & 63;
  int l31 = lane & 31, hi = lane >> 5;
  int lq = l0 + (w << 5) + l31;                 // 8 waves x 32 l

  // scale (k1b folded): sum the 8 per-batch full-Gram dots for this head
  int h = bh & 7;
  float ssum = 0.f;
  #pragma unroll
  for (int nb = 0; nb < 8; ++nb) ssum += ss[(nb << 3) + h];
  float scf = gsim[h] * rsqrtf(ssum * (1.0f / 8388608.0f) + 1e-5f) * 1.44269504089f;

  const short* ktb = Kt  + ((size_t)bh << 16);
  const short* vbb = Vbf + ((size_t)bh << 16);
  const float* qb  = Q   + ((size_t)bh << 16) + lq;

  // Q fragments (B operand), PRE-SCALED by scf (folds BN scale + log2e)
  bf16x8 qf[4];
  #pragma unroll
  for (int kc = 0; kc < 4; ++kc) {
    bf16x8 f;
    #pragma unroll
    for (int i = 0; i < 8; ++i)
      f[i] = (__bf16)(qb[(size_t)((kc << 4) + (hi << 3) + i) << 10] * scf);
    qf[kc] = f;
  }

  // precomputed LDS byte offsets (lane-functions; identical across waves)
  int koff[2][4], voff[2][2][2];
  #pragma unroll
  for (int mt = 0; mt < 2; ++mt) {
    int mrow = (mt << 5) + l31;
    #pragma unroll
    for (int kc = 0; kc < 4; ++kc) {
      int chunk = (kc << 1) + hi;
      koff[mt][kc] = mrow*128 + ((chunk << 4) ^ ((mrow & 7) << 4));
    }
    #pragma unroll
    for (int cz = 0; cz < 2; ++cz) {
      int crow = (cz << 5) + l31;
      #pragma unroll
      for (int j = 0; j < 2; ++j) {
        int chunk = (mt << 2) + (j << 1) + hi;
        voff[mt][cz][j] = crow*128 + ((chunk << 4) ^ ((crow & 7) << 4));
      }
    }
  }

  // prologue: stage tile 0 into buf 0 (512 threads -> one gll16 each for K, V)
  {
    int row = tid >> 3, ch = tid & 7;
    gll16(ktb + ((size_t)row << 6) + ((ch ^ (row & 7)) << 3), &ldsK[0][tid << 3]);
    gll16(vbb + ((size_t)row << 10) + ((ch ^ (row & 7)) << 3), &ldsV[0][tid << 3]);
  }
  __syncthreads();

  f32x16 o0 = z16(), o1 = z16();
  float rsum = 0.f;

  for (int t = 0; t < 16; ++t) {
    int cur = t & 1, nxt = cur ^ 1;
    if (t < 15) {
      int m1 = (t + 1) << 6;
      int row = tid >> 3, ch = tid & 7;
      gll16(ktb + ((size_t)(m1 + row) << 6) + ((ch ^ (row & 7)) << 3), &ldsK[nxt][tid << 3]);
      gll16(vbb + ((size_t)row << 10) + m1 + ((ch ^ (row & 7)) << 3), &ldsV[nxt][tid << 3]);
    }
    #pragma unroll
    for (int mt = 0; mt < 2; ++mt) {
      f32x16 s = z16();
      __builtin_amdgcn_s_setprio(1);
      #pragma unroll
      for (int kc = 0; kc < 4; ++kc) {
        bf16x8 af = *(bf16x8*)((char*)&ldsK[cur][0] + koff[mt][kc]);
        s = __builtin_amdgcn_mfma_f32_32x32x16_bf16(af, qf[kc], s, 0, 0, 0);
      }
      __builtin_amdgcn_s_setprio(0);
      float p[16];
      #pragma unroll
      for (int r = 0; r < 16; ++r) { p[r] = __builtin_amdgcn_exp2f(s[r]); rsum += p[r]; }
      unsigned dw[8];
      #pragma unroll
      for (int j = 0; j < 8; ++j) dw[j] = pkbf(p[2*j], p[2*j+1]);
      u32x2 a0 = __builtin_amdgcn_permlane32_swap(dw[0], dw[2], false, false);
      u32x2 a1 = __builtin_amdgcn_permlane32_swap(dw[1], dw[3], false, false);
      u32x2 a2 = __builtin_amdgcn_permlane32_swap(dw[4], dw[6], false, false);
      u32x2 a3 = __builtin_amdgcn_permlane32_swap(dw[5], dw[7], false, false);
      bf16x8 pb0 = mk8(a0[0], a1[0], a0[1], a1[1]);
      bf16x8 pb1 = mk8(a2[0], a3[0], a2[1], a3[1]);
      __builtin_amdgcn_s_setprio(1);
      {
        bf16x8 va0 = *(bf16x8*)((char*)&ldsV[cur][0] + voff[mt][0][0]);
        o0 = __builtin_amdgcn_mfma_f32_32x32x16_bf16(va0, pb0, o0, 0, 0, 0);
        bf16x8 va1 = *(bf16x8*)((char*)&ldsV[cur][0] + voff[mt][0][1]);
        o0 = __builtin_amdgcn_mfma_f32_32x32x16_bf16(va1, pb1, o0, 0, 0, 0);
      }
      {
        bf16x8 va0 = *(bf16x8*)((char*)&ldsV[cur][0] + voff[mt][1][0]);
        o1 = __builtin_amdgcn_mfma_f32_32x32x16_bf16(va0, pb0, o1, 0, 0, 0);
        bf16x8 va1 = *(bf16x8*)((char*)&ldsV[cur][0] + voff[mt][1][1]);
        o1 = __builtin_amdgcn_mfma_f32_32x32x16_bf16(va1, pb1, o1, 0, 0, 0);
      }
      __builtin_amdgcn_s_setprio(0);
    }
    __syncthreads();
  }

  // softmax denominator: own half + twin half (same column l); direct normalize
  float tot = rsum + __shfl_xor(rsum, 32, 64);
  float inv = 1.0f / tot;
  #pragma unroll
  for (int r = 0; r < 16; ++r) {
    int cr = (r & 3) + ((r >> 2) << 3) + (hi << 2);
    rv[((size_t)(bh*64 + cr) << 10) + lq] = o0[r] * inv;
  }
  #pragma unroll
  for (int r = 0; r < 16; ++r) {
    int cr = 32 + (r & 3) + ((r >> 2) << 3) + (hi << 2);
    rv[((size_t)(bh*64 + cr) << 10) + lq] = o1[r] * inv;
  }
}

// ---------------- K34: per-channel BatchNorm1d + exact GELU (in-place) --------
__global__ __launch_bounds__(256) void k34_bn_gelu(const float* rv,
                                                   const float* __restrict__ gamma_v,
                                                   const float* __restrict__ beta_v,
                                                   float* out) {
  int ch = blockIdx.x;           // = h*64 + c
  int tid = threadIdx.x, w = tid >> 6, lane = tid & 63;
  f32x4 xr[8];
  float s = 0.f, s2 = 0.f;
  #pragma unroll
  for (int b = 0; b < 8; ++b) {
    size_t roff = (((size_t)(b*512 + ch)) << 10) + (tid << 2);
    f32x4 x = *(const f32x4*)(rv + roff);
    xr[b] = x;
    #pragma unroll
    for (int j = 0; j < 4; ++j) { s += x[j]; s2 += x[j]*x[j]; }
  }
  #pragma unroll
  for (int off = 32; off > 0; off >>= 1) { s += __shfl_down(s, off, 64); s2 += __shfl_down(s2, off, 64); }
  __shared__ float red0[4], red1[4];
  __shared__ float ab[2];
  if (lane == 0) { red0[w] = s; red1[w] = s2; }
  __syncthreads();
  if (tid == 0) {
    float S  = red0[0] + red0[1] + red0[2] + red0[3];
    float S2 = red1[0] + red1[1] + red1[2] + red1[3];
    float mean = S * (1.0f / 8192.0f);
    float var  = S2 * (1.0f / 8192.0f) - mean * mean;
    float a = gamma_v[ch] * rsqrtf(var + 1e-5f);
    ab[0] = a; ab[1] = beta_v[ch] - mean * a;
  }
  __syncthreads();
  float a = ab[0], bb = ab[1];
  #pragma unroll
  for (int b = 0; b < 8; ++b) {
    size_t off = (((size_t)(b*512 + ch)) << 10) + (tid << 2);
    f32x4 y;
    #pragma unroll
    for (int j = 0; j < 4; ++j) {
      float v = a * xr[b][j] + bb;
      y[j] = 0.5f * v * (1.0f + erff(v * 0.70710678118f));
    }
    *(f32x4*)(out + off) = y;
  }
}

extern "C" void kernel_launch(void* const* d_in, const int* in_sizes, int n_in,
                              void* d_out, int out_size, void* d_ws, size_t ws_size,
                              hipStream_t stream) {
  const float* q        = (const float*)d_in[0];
  const float* k        = (const float*)d_in[1];
  const float* v        = (const float*)d_in[2];
  const float* gamma_s  = (const float*)d_in[3];
  // d_in[4] = beta_sim: cancels in softmax, unused
  const float* gamma_v  = (const float*)d_in[5];
  const float* beta_v   = (const float*)d_in[6];
  float* out = (float*)d_out;
  char*  ws  = (char*)d_ws;
  short* kt  = (short*)(ws + KT_OFF);
  short* vbf = (short*)(ws + VB_OFF);
  float* ss  = (float*)(ws + SS_OFF);
  float* gm  = (float*)(ws + GM_OFF);

  // ws_size is launch-constant -> branch is deterministic across calls.
  const bool gram2_ok = ws_size >= (size_t)GRAM2_WS_NEED;

  k0_prep<<<1536, 256, 0, stream>>>(k, v, kt, vbf);
  if (gram2_ok) {
    k1a_gram<<<512, 256, 0, stream>>>(q, k, gm);
    k1b_dot <<<64, 256, 0, stream>>>(gm, ss);
  } else {
    k1_gram<<<64, 512, 0, stream>>>(q, k, ss);
  }
  k2_attn8<<<256, 512, 0, stream>>>(q, kt, vbf, ss, gamma_s, out);   // rv in d_out
  k34_bn_gelu<<<512, 256, 0, stream>>>(out, gamma_v, beta_v, out);   // in-place
}

// Round 18
// 68.988 us; speedup vs baseline: 1.0246x; 1.0246x over previous
//
#include <hip/hip_runtime.h>
#include <hip/hip_bf16.h>
#include <math.h>

// dims fixed by setup_inputs: N=8, H=8, D=64, L=M=1024, C=64

typedef __attribute__((ext_vector_type(4)))  float    f32x4;
typedef __attribute__((ext_vector_type(16))) float    f32x16;
typedef __attribute__((ext_vector_type(8)))  __bf16   bf16x8;
typedef __attribute__((ext_vector_type(8)))  short    s16x8;
typedef __attribute__((ext_vector_type(4)))  short    s16x4;
typedef __attribute__((ext_vector_type(2)))  unsigned u32x2;
typedef __attribute__((ext_vector_type(4)))  unsigned u32x4;

// ws layout:
//   Kt  bf16 [64][1024][64]   @ 0        (8 MiB)
//   Vb  bf16 [64][64][1024]   @ 8 MiB    (8 MiB)
//   P1  bf16 [512][1024]      @ 16 MiB   (8 MiB)   (split path only)
//   rsp fp32 [2][64][1024]    @ 24 MiB   (512 KiB) (split path only)
//   ss fp32[64]               @ tail (24.5 MiB / 16 MiB)
//   GM  fp32 [512][6][1024]   @ 32 MiB   (12 MiB)  (2-stage k1 only)
#define KT_OFF 0u
#define VB_OFF (8u*1024u*1024u)
#define P1_OFF (16u*1024u*1024u)
#define RS_OFF (24u*1024u*1024u)
#define GM_OFF (32u*1024u*1024u)
#define SPLIT_WS_NEED (24u*1024u*1024u + 512u*1024u + 4096u)
#define GRAM2_WS_NEED (48u*1024u*1024u)

static __device__ __forceinline__ short bf16s(float f) {
  return __builtin_bit_cast(short, (__bf16)f);
}
static __device__ __forceinline__ unsigned pkbf(float lo, float hi) {
  unsigned l = (unsigned)__builtin_bit_cast(unsigned short, (__bf16)lo);
  unsigned h = (unsigned)__builtin_bit_cast(unsigned short, (__bf16)hi);
  return l | (h << 16);
}
static __device__ __forceinline__ float bf2f(short s) {
  return __builtin_bit_cast(float, ((unsigned)(unsigned short)s) << 16);
}
static __device__ __forceinline__ bf16x8 cvt8(const float* p) {
  f32x4 a = *(const f32x4*)p;
  f32x4 b = *(const f32x4*)(p + 4);
  bf16x8 r;
  r[0]=(__bf16)a[0]; r[1]=(__bf16)a[1]; r[2]=(__bf16)a[2]; r[3]=(__bf16)a[3];
  r[4]=(__bf16)b[0]; r[5]=(__bf16)b[1]; r[6]=(__bf16)b[2]; r[7]=(__bf16)b[3];
  return r;
}
static __device__ __forceinline__ f32x16 z16() {
  f32x16 z;
  #pragma unroll
  for (int i = 0; i < 16; ++i) z[i] = 0.f;
  return z;
}
static __device__ __forceinline__ bf16x8 mk8(unsigned a, unsigned b, unsigned c, unsigned d) {
  u32x4 u; u[0]=a; u[1]=b; u[2]=c; u[3]=d;
  return __builtin_bit_cast(bf16x8, u);
}
static __device__ __forceinline__ void gll16(const void* g, void* l) {
  __builtin_amdgcn_global_load_lds(
      (const __attribute__((address_space(1))) void*)g,
      (__attribute__((address_space(3))) void*)l, 16, 0, 0);
}

// ---- K0: blocks<1024: K [bh][d][m] -> Kt [bh][m][d] bf16; rest: V -> Vb bf16 --
__global__ __launch_bounds__(256) void k0_prep(const float* __restrict__ K,
                                               const float* __restrict__ V,
                                               short* __restrict__ Kt,
                                               short* __restrict__ Vb) {
  int tid = threadIdx.x;
  if (blockIdx.x < 1024) {
    int bh = blockIdx.x >> 4;
    int m0 = (blockIdx.x & 15) << 6;
    __shared__ short tile[64][72];          // [m][d], +8 pad
    int d = tid >> 2;
    #pragma unroll
    for (int it = 0; it < 4; ++it) {
      int mc4 = (tid & 3) + (it << 2);
      const f32x4 v = *(const f32x4*)(K + (((size_t)(bh*64 + d)) << 10) + m0 + (mc4 << 2));
      #pragma unroll
      for (int j = 0; j < 4; ++j) tile[mc4*4 + j][d] = bf16s(v[j]);
    }
    __syncthreads();
    int m = tid >> 2, q = tid & 3;
    s16x8 o0, o1;
    #pragma unroll
    for (int j = 0; j < 8; ++j) { o0[j] = tile[m][q*16 + j]; o1[j] = tile[m][q*16 + 8 + j]; }
    short* dst = Kt + ((size_t)bh << 16) + ((size_t)(m0 + m) << 6) + (q << 4);
    *(s16x8*)dst = o0;
    *(s16x8*)(dst + 8) = o1;
  } else {
    // streaming fp32 -> bf16 convert of V (no transpose; PV consumes [c][m] rows)
    size_t base = ((size_t)(blockIdx.x - 1024)) << 13;   // 8192 elems per block
    #pragma unroll
    for (int it = 0; it < 8; ++it) {
      size_t idx = base + ((size_t)it << 10) + (tid << 2);
      f32x4 x = *(const f32x4*)(V + idx);
      s16x4 y;
      #pragma unroll
      for (int j = 0; j < 4; ++j) y[j] = bf16s(x[j]);
      *(s16x4*)(Vb + idx) = y;
    }
  }
}

// ---- K1a (stage A): partial Grams per (bh, l-slice) -> gm, full-chip grid ----
__global__ __launch_bounds__(256) void k1a_gram(const float* __restrict__ Q,
                                                const float* __restrict__ K,
                                                float* __restrict__ gm) {
  int bh = blockIdx.x >> 3, sl = blockIdx.x & 7;
  int tid = threadIdx.x, w = tid >> 6, lane = tid & 63;
  int l31 = lane & 31, hi = lane >> 5;
  const float* qlo = Q + ((size_t)bh << 16) + ((size_t)l31 << 10);
  const float* qhi = qlo + (32u << 10);
  const float* klo = K + ((size_t)bh << 16) + ((size_t)l31 << 10);
  const float* khi = klo + (32u << 10);
  f32x16 gq00 = z16(), gq01 = z16(), gq11 = z16();
  f32x16 gk00 = z16(), gk01 = z16(), gk11 = z16();
  #pragma unroll
  for (int lc = 0; lc < 2; ++lc) {
    int loff = (sl << 7) + (w << 5) + (lc << 4) + (hi << 3);
    bf16x8 aql = cvt8(qlo + loff), aqh = cvt8(qhi + loff);
    bf16x8 akl = cvt8(klo + loff), akh = cvt8(khi + loff);
    gq00 = __builtin_amdgcn_mfma_f32_32x32x16_bf16(aql, aql, gq00, 0, 0, 0);
    gq01 = __builtin_amdgcn_mfma_f32_32x32x16_bf16(aql, aqh, gq01, 0, 0, 0);
    gq11 = __builtin_amdgcn_mfma_f32_32x32x16_bf16(aqh, aqh, gq11, 0, 0, 0);
    gk00 = __builtin_amdgcn_mfma_f32_32x32x16_bf16(akl, akl, gk00, 0, 0, 0);
    gk01 = __builtin_amdgcn_mfma_f32_32x32x16_bf16(akl, akh, gk01, 0, 0, 0);
    gk11 = __builtin_amdgcn_mfma_f32_32x32x16_bf16(akh, akh, gk11, 0, 0, 0);
  }
  __shared__ float RQ[4][64][16];
  __shared__ float RK[4][64][16];
  float* gout = gm + ((size_t)blockIdx.x * 6144u);
  #define K1A_RED(GQ_, GK_, TI_)                                            \
    __syncthreads();                                                        \
    _Pragma("unroll")                                                       \
    for (int r = 0; r < 16; ++r) { RQ[w][lane][r] = GQ_[r]; RK[w][lane][r] = GK_[r]; } \
    __syncthreads();                                                        \
    {                                                                       \
      int e = tid & 63, rq = (tid >> 6) << 2;                               \
      f32x4 aq, ak;                                                         \
      _Pragma("unroll")                                                     \
      for (int j = 0; j < 4; ++j) {                                         \
        int r = rq + j;                                                     \
        aq[j] = RQ[0][e][r] + RQ[1][e][r] + RQ[2][e][r] + RQ[3][e][r];      \
        ak[j] = RK[0][e][r] + RK[1][e][r] + RK[2][e][r] + RK[3][e][r];      \
      }                                                                     \
      *(f32x4*)(gout + (TI_)*1024 + (e << 4) + rq) = aq;                    \
      *(f32x4*)(gout + ((TI_) + 3)*1024 + (e << 4) + rq) = ak;              \
    }
  K1A_RED(gq00, gk00, 0)
  K1A_RED(gq01, gk01, 1)
  K1A_RED(gq11, gk11, 2)
  #undef K1A_RED
}

// ---- K1b (stage B): ss[bh] = sum slices, then dot (weights 1,2,1) ------------
__global__ __launch_bounds__(256) void k1b_dot(const float* __restrict__ gm,
                                               float* __restrict__ ss) {
  int bh = blockIdx.x;
  int tid = threadIdx.x, w = tid >> 6, lane = tid & 63;
  float part = 0.f;
  #pragma unroll
  for (int t = 0; t < 3; ++t) {
    f32x4 aq = {0.f, 0.f, 0.f, 0.f}, ak = {0.f, 0.f, 0.f, 0.f};
    #pragma unroll
    for (int s = 0; s < 8; ++s) {
      const float* base = gm + ((size_t)((bh << 3) + s) * 6144u) + (size_t)t*1024u + (tid << 2);
      aq += *(const f32x4*)base;
      ak += *(const f32x4*)(base + 3*1024);
    }
    float d = aq[0]*ak[0] + aq[1]*ak[1] + aq[2]*ak[2] + aq[3]*ak[3];
    part += (t == 1) ? 2.0f * d : d;
  }
  #pragma unroll
  for (int off = 32; off > 0; off >>= 1) part += __shfl_down(part, off, 64);
  __shared__ float red[4];
  if (lane == 0) red[w] = part;
  __syncthreads();
  if (tid == 0) ss[bh] = red[0] + red[1] + red[2] + red[3];
}

// ---- K1 fallback (ws too small): r11-proven 64-block full-Gram version -------
__global__ __launch_bounds__(512) void k1_gram(const float* __restrict__ Q,
                                               const float* __restrict__ K,
                                               float* __restrict__ ss) {
  int bh = blockIdx.x;
  int tid = threadIdx.x, w = tid >> 6, lane = tid & 63;
  int l31 = lane & 31, hi = lane >> 5;
  const float* qlo = Q + ((size_t)bh << 16) + ((size_t)l31 << 10);
  const float* qhi = qlo + (32u << 10);
  const float* klo = K + ((size_t)bh << 16) + ((size_t)l31 << 10);
  const float* khi = klo + (32u << 10);
  f32x16 gq00 = z16(), gq01 = z16(), gq11 = z16();
  f32x16 gk00 = z16(), gk01 = z16(), gk11 = z16();
  for (int lc = 0; lc < 8; ++lc) {
    int loff = (w << 7) + (lc << 4) + (hi << 3);
    bf16x8 aql = cvt8(qlo + loff), aqh = cvt8(qhi + loff);
    bf16x8 akl = cvt8(klo + loff), akh = cvt8(khi + loff);
    gq00 = __builtin_amdgcn_mfma_f32_32x32x16_bf16(aql, aql, gq00, 0, 0, 0);
    gq01 = __builtin_amdgcn_mfma_f32_32x32x16_bf16(aql, aqh, gq01, 0, 0, 0);
    gq11 = __builtin_amdgcn_mfma_f32_32x32x16_bf16(aqh, aqh, gq11, 0, 0, 0);
    gk00 = __builtin_amdgcn_mfma_f32_32x32x16_bf16(akl, akl, gk00, 0, 0, 0);
    gk01 = __builtin_amdgcn_mfma_f32_32x32x16_bf16(akl, akh, gk01, 0, 0, 0);
    gk11 = __builtin_amdgcn_mfma_f32_32x32x16_bf16(akh, akh, gk11, 0, 0, 0);
  }
  __shared__ float RQ[8][64][16];
  __shared__ float RK[8][64][16];
  float part = 0.f;
  #define K1_REDUCE(GQ_, GK_, WT_)                                          \
    __syncthreads();                                                        \
    _Pragma("unroll")                                                       \
    for (int r = 0; r < 16; ++r) { RQ[w][lane][r] = GQ_[r]; RK[w][lane][r] = GK_[r]; } \
    __syncthreads();                                                        \
    if (tid < 256) {                                                        \
      int e = tid & 63, rq = (tid >> 6) << 2;                               \
      _Pragma("unroll")                                                     \
      for (int j = 0; j < 4; ++j) {                                         \
        int r = rq + j;                                                     \
        float aq = 0.f, ak = 0.f;                                           \
        _Pragma("unroll")                                                   \
        for (int ww = 0; ww < 8; ++ww) { aq += RQ[ww][e][r]; ak += RK[ww][e][r]; } \
        part += (WT_) * aq * ak;                                            \
      }                                                                     \
    }
  K1_REDUCE(gq00, gk00, 1.0f)
  K1_REDUCE(gq01, gk01, 2.0f)
  K1_REDUCE(gq11, gk11, 1.0f)
  #undef K1_REDUCE
  #pragma unroll
  for (int off = 32; off > 0; off >>= 1) part += __shfl_down(part, off, 64);
  __shared__ float red[8];
  __syncthreads();
  if (lane == 0) red[w] = part;
  __syncthreads();
  if (tid == 0) {
    float s = 0.f;
    #pragma unroll
    for (int ww = 0; ww < 8; ++ww) s += red[ww];
    ss[bh] = s;
  }
}

// ------- K2 (split path): 8 waves share each K/V tile (256 l per block) -------
__global__ __launch_bounds__(512) void k2_attn8(const float* __restrict__ Q,
                                                const short* __restrict__ Kt,
                                                const short* __restrict__ Vbf,
                                                const float* __restrict__ ss,
                                                const float* __restrict__ gsim,
                                                float* __restrict__ rv,
                                                short* __restrict__ p1,
                                                float* __restrict__ rsp) {
  __shared__ short ldsK[2][4096];   // [64 m][8 chunks of 8 d] bf16, XOR-swizzled
  __shared__ short ldsV[2][4096];   // [64 c][8 chunks of 8 m] bf16, same swizzle
  int b = blockIdx.x;               // 512 blocks: bh x 2 slab(256 l) x 2 mh
  int bh   = (b & 7) + (((b >> 3) & 7) << 3);   // same bh -> same XCD (round-robin %8)
  int rest = b >> 6;                            // slab*2 + mh, slab in [0,4)
  int slab = rest >> 1;
  int mh   = rest & 1;
  int tbase = mh << 3;
  int l0 = slab << 8;                           // 256 l per block
  int tid = threadIdx.x, w = tid >> 6, lane = tid & 63;
  int l31 = lane & 31, hi = lane >> 5;
  int lq = l0 + (w << 5) + l31;                 // 8 waves x 32 l

  // scale (k1b folded): sum the 8 per-batch full-Gram dots for this head
  int h = bh & 7;
  float ssum = 0.f;
  #pragma unroll
  for (int nb = 0; nb < 8; ++nb) ssum += ss[(nb << 3) + h];
  float scf = gsim[h] * rsqrtf(ssum * (1.0f / 8388608.0f) + 1e-5f) * 1.44269504089f;

  const short* ktb = Kt  + ((size_t)bh << 16);
  const short* vbb = Vbf + ((size_t)bh << 16);
  const float* qb  = Q   + ((size_t)bh << 16) + lq;

  // Q fragments (B operand), PRE-SCALED by scf (folds BN scale + log2e)
  bf16x8 qf[4];
  #pragma unroll
  for (int kc = 0; kc < 4; ++kc) {
    bf16x8 f;
    #pragma unroll
    for (int i = 0; i < 8; ++i)
      f[i] = (__bf16)(qb[(size_t)((kc << 4) + (hi << 3) + i) << 10] * scf);
    qf[kc] = f;
  }

  // precomputed LDS byte offsets (lane-functions; identical across waves)
  int koff[2][4], voff[2][2][2];
  #pragma unroll
  for (int mt = 0; mt < 2; ++mt) {
    int mrow = (mt << 5) + l31;
    #pragma unroll
    for (int kc = 0; kc < 4; ++kc) {
      int chunk = (kc << 1) + hi;
      koff[mt][kc] = mrow*128 + ((chunk << 4) ^ ((mrow & 7) << 4));
    }
    #pragma unroll
    for (int cz = 0; cz < 2; ++cz) {
      int crow = (cz << 5) + l31;
      #pragma unroll
      for (int j = 0; j < 2; ++j) {
        int chunk = (mt << 2) + (j << 1) + hi;
        voff[mt][cz][j] = crow*128 + ((chunk << 4) ^ ((crow & 7) << 4));
      }
    }
  }

  // prologue: stage tile tbase into buf 0 (512 threads -> one pass each)
  {
    int m0 = tbase << 6;
    int row = tid >> 3, ch = tid & 7;
    gll16(ktb + ((size_t)(m0 + row) << 6) + ((ch ^ (row & 7)) << 3), &ldsK[0][tid << 3]);
    gll16(vbb + ((size_t)row << 10) + m0 + ((ch ^ (row & 7)) << 3), &ldsV[0][tid << 3]);
  }
  __syncthreads();

  f32x16 o0 = z16(), o1 = z16();
  float rsum = 0.f;

  for (int t = 0; t < 8; ++t) {
    int cur = t & 1, nxt = cur ^ 1;
    if (t < 7) {
      int m1 = (tbase + t + 1) << 6;
      int row = tid >> 3, ch = tid & 7;
      gll16(ktb + ((size_t)(m1 + row) << 6) + ((ch ^ (row & 7)) << 3), &ldsK[nxt][tid << 3]);
      gll16(vbb + ((size_t)row << 10) + m1 + ((ch ^ (row & 7)) << 3), &ldsV[nxt][tid << 3]);
    }
    #pragma unroll
    for (int mt = 0; mt < 2; ++mt) {
      f32x16 s = z16();
      __builtin_amdgcn_s_setprio(1);
      #pragma unroll
      for (int kc = 0; kc < 4; ++kc) {
        bf16x8 af = *(bf16x8*)((char*)&ldsK[cur][0] + koff[mt][kc]);
        s = __builtin_amdgcn_mfma_f32_32x32x16_bf16(af, qf[kc], s, 0, 0, 0);
      }
      __builtin_amdgcn_s_setprio(0);
      float p[16];
      #pragma unroll
      for (int r = 0; r < 16; ++r) { p[r] = __builtin_amdgcn_exp2f(s[r]); rsum += p[r]; }
      unsigned dw[8];
      #pragma unroll
      for (int j = 0; j < 8; ++j) dw[j] = pkbf(p[2*j], p[2*j+1]);
      u32x2 a0 = __builtin_amdgcn_permlane32_swap(dw[0], dw[2], false, false);
      u32x2 a1 = __builtin_amdgcn_permlane32_swap(dw[1], dw[3], false, false);
      u32x2 a2 = __builtin_amdgcn_permlane32_swap(dw[4], dw[6], false, false);
      u32x2 a3 = __builtin_amdgcn_permlane32_swap(dw[5], dw[7], false, false);
      bf16x8 pb0 = mk8(a0[0], a1[0], a0[1], a1[1]);
      bf16x8 pb1 = mk8(a2[0], a3[0], a2[1], a3[1]);
      __builtin_amdgcn_s_setprio(1);
      {
        bf16x8 va0 = *(bf16x8*)((char*)&ldsV[cur][0] + voff[mt][0][0]);
        o0 = __builtin_amdgcn_mfma_f32_32x32x16_bf16(va0, pb0, o0, 0, 0, 0);
        bf16x8 va1 = *(bf16x8*)((char*)&ldsV[cur][0] + voff[mt][0][1]);
        o0 = __builtin_amdgcn_mfma_f32_32x32x16_bf16(va1, pb1, o0, 0, 0, 0);
      }
      {
        bf16x8 va0 = *(bf16x8*)((char*)&ldsV[cur][0] + voff[mt][1][0]);
        o1 = __builtin_amdgcn_mfma_f32_32x32x16_bf16(va0, pb0, o1, 0, 0, 0);
        bf16x8 va1 = *(bf16x8*)((char*)&ldsV[cur][0] + voff[mt][1][1]);
        o1 = __builtin_amdgcn_mfma_f32_32x32x16_bf16(va1, pb1, o1, 0, 0, 0);
      }
      __builtin_amdgcn_s_setprio(0);
    }
    __syncthreads();
  }

  // partial denominator for this m-range: own half + twin half (same column l)
  float tot = rsum + __shfl_xor(rsum, 32, 64);
  if (mh == 0) {
    #pragma unroll
    for (int r = 0; r < 16; ++r) {
      int cr = (r & 3) + ((r >> 2) << 3) + (hi << 2);
      rv[((size_t)(bh*64 + cr) << 10) + lq] = o0[r];
    }
    #pragma unroll
    for (int r = 0; r < 16; ++r) {
      int cr = 32 + (r & 3) + ((r >> 2) << 3) + (hi << 2);
      rv[((size_t)(bh*64 + cr) << 10) + lq] = o1[r];
    }
  } else {
    #pragma unroll
    for (int r = 0; r < 16; ++r) {
      int cr = (r & 3) + ((r >> 2) << 3) + (hi << 2);
      p1[((size_t)(bh*64 + cr) << 10) + lq] = bf16s(o0[r]);
    }
    #pragma unroll
    for (int r = 0; r < 16; ++r) {
      int cr = 32 + (r & 3) + ((r >> 2) << 3) + (hi << 2);
      p1[((size_t)(bh*64 + cr) << 10) + lq] = bf16s(o1[r]);
    }
  }
  if (hi == 0) rsp[(mh << 16) + (bh << 10) + lq] = tot;
}

// ------- K2 fallback (ws too small): r12-proven non-split 256-thread path -----
__global__ __launch_bounds__(256) void k2_attn_ns(const float* __restrict__ Q,
                                                  const short* __restrict__ Kt,
                                                  const short* __restrict__ Vbf,
                                                  const float* __restrict__ ss,
                                                  const float* __restrict__ gsim,
                                                  float* __restrict__ rv) {
  __shared__ short ldsK[2][4096];
  __shared__ short ldsV[2][4096];
  int b = blockIdx.x;
  int bh   = (b & 7) + (((b >> 3) & 7) << 3);
  int slab = b >> 6;
  int l0 = slab << 7;
  int tid = threadIdx.x, w = tid >> 6, lane = tid & 63;
  int l31 = lane & 31, hi = lane >> 5;
  int lq = l0 + (w << 5) + l31;
  int h = bh & 7;
  float ssum = 0.f;
  #pragma unroll
  for (int nb = 0; nb < 8; ++nb) ssum += ss[(nb << 3) + h];
  float scf = gsim[h] * rsqrtf(ssum * (1.0f / 8388608.0f) + 1e-5f) * 1.44269504089f;
  const short* ktb = Kt  + ((size_t)bh << 16);
  const short* vbb = Vbf + ((size_t)bh << 16);
  const float* qb  = Q   + ((size_t)bh << 16) + lq;
  bf16x8 qf[4];
  #pragma unroll
  for (int kc = 0; kc < 4; ++kc) {
    bf16x8 f;
    #pragma unroll
    for (int i = 0; i < 8; ++i)
      f[i] = (__bf16)(qb[(size_t)((kc << 4) + (hi << 3) + i) << 10] * scf);
    qf[kc] = f;
  }
  int koff[2][4], voff[2][2][2];
  #pragma unroll
  for (int mt = 0; mt < 2; ++mt) {
    int mrow = (mt << 5) + l31;
    #pragma unroll
    for (int kc = 0; kc < 4; ++kc) {
      int chunk = (kc << 1) + hi;
      koff[mt][kc] = mrow*128 + ((chunk << 4) ^ ((mrow & 7) << 4));
    }
    #pragma unroll
    for (int cz = 0; cz < 2; ++cz) {
      int crow = (cz << 5) + l31;
      #pragma unroll
      for (int j = 0; j < 2; ++j) {
        int chunk = (mt << 2) + (j << 1) + hi;
        voff[mt][cz][j] = crow*128 + ((chunk << 4) ^ ((crow & 7) << 4));
      }
    }
  }
  {
    #pragma unroll
    for (int p = 0; p < 2; ++p) {
      int idx = (p << 8) + tid, row = idx >> 3, ch = idx & 7;
      gll16(ktb + ((size_t)row << 6) + ((ch ^ (row & 7)) << 3), &ldsK[0][idx << 3]);
      gll16(vbb + ((size_t)row << 10) + ((ch ^ (row & 7)) << 3), &ldsV[0][idx << 3]);
    }
  }
  __syncthreads();
  f32x16 o0 = z16(), o1 = z16();
  float rsum = 0.f;
  for (int t = 0; t < 16; ++t) {
    int cur = t & 1, nxt = cur ^ 1;
    if (t < 15) {
      int m1 = (t + 1) << 6;
      #pragma unroll
      for (int p = 0; p < 2; ++p) {
        int idx = (p << 8) + tid, row = idx >> 3, ch = idx & 7;
        gll16(ktb + ((size_t)(m1 + row) << 6) + ((ch ^ (row & 7)) << 3), &ldsK[nxt][idx << 3]);
        gll16(vbb + ((size_t)row << 10) + m1 + ((ch ^ (row & 7)) << 3), &ldsV[nxt][idx << 3]);
      }
    }
    #pragma unroll
    for (int mt = 0; mt < 2; ++mt) {
      f32x16 s = z16();
      #pragma unroll
      for (int kc = 0; kc < 4; ++kc) {
        bf16x8 af = *(bf16x8*)((char*)&ldsK[cur][0] + koff[mt][kc]);
        s = __builtin_amdgcn_mfma_f32_32x32x16_bf16(af, qf[kc], s, 0, 0, 0);
      }
      float p[16];
      #pragma unroll
      for (int r = 0; r < 16; ++r) { p[r] = __builtin_amdgcn_exp2f(s[r]); rsum += p[r]; }
      unsigned dw[8];
      #pragma unroll
      for (int j = 0; j < 8; ++j) dw[j] = pkbf(p[2*j], p[2*j+1]);
      u32x2 a0 = __builtin_amdgcn_permlane32_swap(dw[0], dw[2], false, false);
      u32x2 a1 = __builtin_amdgcn_permlane32_swap(dw[1], dw[3], false, false);
      u32x2 a2 = __builtin_amdgcn_permlane32_swap(dw[4], dw[6], false, false);
      u32x2 a3 = __builtin_amdgcn_permlane32_swap(dw[5], dw[7], false, false);
      bf16x8 pb0 = mk8(a0[0], a1[0], a0[1], a1[1]);
      bf16x8 pb1 = mk8(a2[0], a3[0], a2[1], a3[1]);
      {
        bf16x8 va0 = *(bf16x8*)((char*)&ldsV[cur][0] + voff[mt][0][0]);
        o0 = __builtin_amdgcn_mfma_f32_32x32x16_bf16(va0, pb0, o0, 0, 0, 0);
        bf16x8 va1 = *(bf16x8*)((char*)&ldsV[cur][0] + voff[mt][0][1]);
        o0 = __builtin_amdgcn_mfma_f32_32x32x16_bf16(va1, pb1, o0, 0, 0, 0);
      }
      {
        bf16x8 va0 = *(bf16x8*)((char*)&ldsV[cur][0] + voff[mt][1][0]);
        o1 = __builtin_amdgcn_mfma_f32_32x32x16_bf16(va0, pb0, o1, 0, 0, 0);
        bf16x8 va1 = *(bf16x8*)((char*)&ldsV[cur][0] + voff[mt][1][1]);
        o1 = __builtin_amdgcn_mfma_f32_32x32x16_bf16(va1, pb1, o1, 0, 0, 0);
      }
    }
    __syncthreads();
  }
  float tot = rsum + __shfl_xor(rsum, 32, 64);
  float inv = 1.0f / tot;
  #pragma unroll
  for (int r = 0; r < 16; ++r) {
    int cr = (r & 3) + ((r >> 2) << 3) + (hi << 2);
    rv[((size_t)(bh*64 + cr) << 10) + lq] = o0[r] * inv;
  }
  #pragma unroll
  for (int r = 0; r < 16; ++r) {
    int cr = 32 + (r & 3) + ((r >> 2) << 3) + (hi << 2);
    rv[((size_t)(bh*64 + cr) << 10) + lq] = o1[r] * inv;
  }
}

// ---------------- K34: combine partials + per-channel BatchNorm1d + GELU ------
template<bool SPLIT>
__global__ __launch_bounds__(256) void k34_bn_gelu(const float* rv,
                                                   const short* __restrict__ p1,
                                                   const float* __restrict__ rsp,
                                                   const float* __restrict__ gamma_v,
                                                   const float* __restrict__ beta_v,
                                                   float* out) {
  int ch = blockIdx.x;           // = h*64 + c
  int h  = ch >> 6;
  int tid = threadIdx.x, w = tid >> 6, lane = tid & 63;
  f32x4 xr[8];
  float s = 0.f, s2 = 0.f;
  #pragma unroll
  for (int b = 0; b < 8; ++b) {
    size_t roff = (((size_t)(b*512 + ch)) << 10) + (tid << 2);
    f32x4 x = *(const f32x4*)(rv + roff);
    if constexpr (SPLIT) {
      s16x4 pp = *(const s16x4*)(p1 + roff);
      size_t soff = (((size_t)(b*8 + h)) << 10) + (tid << 2);
      f32x4 r0 = *(const f32x4*)(rsp + soff);
      f32x4 r1 = *(const f32x4*)(rsp + 65536 + soff);
      #pragma unroll
      for (int j = 0; j < 4; ++j)
        x[j] = (x[j] + bf2f(pp[j])) / (r0[j] + r1[j]);
    }
    xr[b] = x;
    #pragma unroll
    for (int j = 0; j < 4; ++j) { s += x[j]; s2 += x[j]*x[j]; }
  }
  #pragma unroll
  for (int off = 32; off > 0; off >>= 1) { s += __shfl_down(s, off, 64); s2 += __shfl_down(s2, off, 64); }
  __shared__ float red0[4], red1[4];
  __shared__ float ab[2];
  if (lane == 0) { red0[w] = s; red1[w] = s2; }
  __syncthreads();
  if (tid == 0) {
    float S  = red0[0] + red0[1] + red0[2] + red0[3];
    float S2 = red1[0] + red1[1] + red1[2] + red1[3];
    float mean = S * (1.0f / 8192.0f);
    float var  = S2 * (1.0f / 8192.0f) - mean * mean;
    float a = gamma_v[ch] * rsqrtf(var + 1e-5f);
    ab[0] = a; ab[1] = beta_v[ch] - mean * a;
  }
  __syncthreads();
  float a = ab[0], bb = ab[1];
  #pragma unroll
  for (int b = 0; b < 8; ++b) {
    size_t off = (((size_t)(b*512 + ch)) << 10) + (tid << 2);
    f32x4 y;
    #pragma unroll
    for (int j = 0; j < 4; ++j) {
      float v = a * xr[b][j] + bb;
      y[j] = 0.5f * v * (1.0f + erff(v * 0.70710678118f));
    }
    *(f32x4*)(out + off) = y;
  }
}

extern "C" void kernel_launch(void* const* d_in, const int* in_sizes, int n_in,
                              void* d_out, int out_size, void* d_ws, size_t ws_size,
                              hipStream_t stream) {
  const float* q        = (const float*)d_in[0];
  const float* k        = (const float*)d_in[1];
  const float* v        = (const float*)d_in[2];
  const float* gamma_s  = (const float*)d_in[3];
  // d_in[4] = beta_sim: cancels in softmax, unused
  const float* gamma_v  = (const float*)d_in[5];
  const float* beta_v   = (const float*)d_in[6];
  float* out = (float*)d_out;
  char*  ws  = (char*)d_ws;
  short* kt  = (short*)(ws + KT_OFF);
  short* vbf = (short*)(ws + VB_OFF);
  short* p1  = (short*)(ws + P1_OFF);
  float* rsp = (float*)(ws + RS_OFF);
  float* gm  = (float*)(ws + GM_OFF);

  // ws_size is launch-constant -> branches are deterministic across calls.
  const bool split_ok = ws_size >= (size_t)SPLIT_WS_NEED;
  const bool gram2_ok = ws_size >= (size_t)GRAM2_WS_NEED;
  size_t tail = split_ok ? (size_t)(24u*1024u*1024u + 512u*1024u)
                         : (size_t)(16u*1024u*1024u);
  float* ss = (float*)(ws + tail);

  k0_prep<<<1536, 256, 0, stream>>>(k, v, kt, vbf);
  if (gram2_ok) {
    k1a_gram<<<512, 256, 0, stream>>>(q, k, gm);
    k1b_dot <<<64, 256, 0, stream>>>(gm, ss);
  } else {
    k1_gram<<<64, 512, 0, stream>>>(q, k, ss);
  }
  if (split_ok) {
    k2_attn8<<<512, 512, 0, stream>>>(q, kt, vbf, ss, gamma_s, out, p1, rsp);
    k34_bn_gelu<true ><<<512, 256, 0, stream>>>(out, p1, rsp, gamma_v, beta_v, out);
  } else {
    k2_attn_ns<<<512, 256, 0, stream>>>(q, kt, vbf, ss, gamma_s, out);
    k34_bn_gelu<false><<<512, 256, 0, stream>>>(out, p1, rsp, gamma_v, beta_v, out);
  }
}